// Round 10
// baseline (288.447 us; speedup 1.0000x reference)
//
#include <hip/hip_runtime.h>
#include <hip/hip_bf16.h>

typedef unsigned short u16;
typedef __bf16 bf16x8 __attribute__((ext_vector_type(8)));
typedef __bf16 bf16x4 __attribute__((ext_vector_type(4)));
typedef float f32x4 __attribute__((ext_vector_type(4)));
typedef unsigned int uint32x2 __attribute__((ext_vector_type(2)));

#define MFMA16(a, b, c) __builtin_amdgcn_mfma_f32_16x16x32_bf16(a, b, c, 0, 0, 0)

// exp(z/8) = exp2(z * log2(e)/8); folded into fkF at projection time.
#define FK_SCALE 0.1803368801111204f  // 0.125 * log2(e)

#define NSPLIT 16

// ---------------------------------------------------------------------------
// MFMA projections (bf16 in / fp32 acc). One wave per (proj, b, 64-l chunk):
// grid 768 x 64thr, bx = p*256 + b*64 + chunk.
//  p=0 fk: C[kout][l] = Wfk(A) . field(B), scaled, +bias -> fkF (A-frag order)
//  p=1 fv: C[l][v]    = field(A) . Wfv(B), +bias         -> fvF (A-frag order)
//  p=2 hk: C[kout][q] = Wqk(A) . query(B), +bias         -> hkF (B-frag order,
//          same store algebra as p=0 with l<->q)
// ---------------------------------------------------------------------------
__global__ __launch_bounds__(64, 2) void proj_kernel(
    const float* __restrict__ field, const float* __restrict__ query,
    const float* __restrict__ Wfk, const float* __restrict__ bfk,
    const float* __restrict__ Wfv, const float* __restrict__ bfv,
    const float* __restrict__ Wqk, const float* __restrict__ bqk,
    u16* __restrict__ fkF, u16* __restrict__ fvF, u16* __restrict__ hkF) {
  const int lane = threadIdx.x;
  const int q15 = lane & 15, quad = lane >> 4;
  const int bx = blockIdx.x;
  const int p = bx >> 8;          // 0=fk, 1=fv, 2=hk
  const int b = (bx >> 6) & 3;
  const int l0 = (bx & 63) * 64;

  const float* src  = (p == 2) ? query : field;
  const float* W    = (p == 0) ? Wfk : (p == 1) ? Wfv : Wqk;
  const float* bias = (p == 0) ? bfk : (p == 1) ? bfv : bqk;
  const float* sp = src + (size_t)b * (128 * 4096);

  // src frags: p!=1: B[k=f][n=l]; p==1: A[m=l][k=f] (same lane mapping).
  bf16x8 fr1[4][4];
#pragma unroll
  for (int t = 0; t < 4; ++t)
#pragma unroll
    for (int ks = 0; ks < 4; ++ks) {
      const float* pp = sp + (size_t)(ks * 32 + quad * 8) * 4096 + l0 + t * 16 + q15;
      bf16x8 v;
#pragma unroll
      for (int j = 0; j < 8; ++j) v[j] = (__bf16)pp[(size_t)j * 4096];
      fr1[t][ks] = v;
    }

  // W frags: p!=1: A[m=kout][k=f]; p==1: B[k=f][n=v].
  bf16x8 fr2[4][4];
#pragma unroll
  for (int t = 0; t < 4; ++t)
#pragma unroll
    for (int ks = 0; ks < 4; ++ks) {
      const float* pp = W + (size_t)(t * 16 + q15) * 128 + ks * 32 + quad * 8;
      f32x4 w0 = *reinterpret_cast<const f32x4*>(pp);
      f32x4 w1 = *reinterpret_cast<const f32x4*>(pp + 4);
      bf16x8 v;
#pragma unroll
      for (int j = 0; j < 4; ++j) { v[j] = (__bf16)w0[j]; v[4 + j] = (__bf16)w1[j]; }
      fr2[t][ks] = v;
    }

#pragma unroll
  for (int nn = 0; nn < 4; ++nn) {
    f32x4 Cn[4];
#pragma unroll
    for (int mm = 0; mm < 4; ++mm) Cn[mm] = (f32x4){0.f, 0.f, 0.f, 0.f};
#pragma unroll
    for (int ks = 0; ks < 4; ++ks)
#pragma unroll
      for (int mm = 0; mm < 4; ++mm)
        Cn[mm] = (p == 1) ? MFMA16(fr1[mm][ks], fr2[nn][ks], Cn[mm])
                          : MFMA16(fr2[mm][ks], fr1[nn][ks], Cn[mm]);

    if (p == 1) {
      // C rows = l = l0+mm*16+quad*4+r, cols = v = nn*16+q15
      const float bv = bias[nn * 16 + q15];
#pragma unroll
      for (int mm = 0; mm < 4; ++mm) {
        bf16x4 o;
#pragma unroll
        for (int r = 0; r < 4; ++r) o[r] = (__bf16)(Cn[mm][r] + bv);
        u16* dst = fvF +
            ((size_t)((b * 4 + nn) * 64 + (l0 >> 6)) * 2 + (mm >> 1)) * 512 +
            (((2 * mm + (quad >> 1)) & 3) * 16 + q15) * 8 + (quad & 1) * 4;
        *reinterpret_cast<uint32x2*>(dst) = __builtin_bit_cast(uint32x2, o);
      }
    } else {
      // C rows = kout = mm*16+quad*4+r, cols = (l or q) = l0+nn*16+q15.
      const float cs = (p == 0) ? FK_SCALE : 1.0f;
      u16* outF = (p == 0) ? fkF : hkF;
#pragma unroll
      for (int mm = 0; mm < 4; ++mm) {
        f32x4 bz = *reinterpret_cast<const f32x4*>(bias + mm * 16 + quad * 4);
        bf16x4 o;
#pragma unroll
        for (int r = 0; r < 4; ++r) o[r] = (__bf16)((Cn[mm][r] + bz[r]) * cs);
        u16* dst = outF +
            ((size_t)((b * 256 + (l0 >> 4) + nn) * 2) + (mm >> 1)) * 512 +
            (((2 * mm + (quad >> 1)) & 3) * 16 + q15) * 8 + (quad & 1) * 4;
        *reinterpret_cast<uint32x2*>(dst) = __builtin_bit_cast(uint32x2, o);
      }
    }
  }
}

// ---------------------------------------------------------------------------
// Attention: barrier-free, single 8KB LDS buffer (PV-then-S order; DS ops
// are wave-ordered so read-before-overwrite is safe -- structure validated
// in R8, whose regression was purely the atomics). NSPLIT=16 -> grid 4096 =
// 16 waves/CU demanded; denominator moved to VALU dsum (drops 16 AGPR) so
// ~164 total regs fit __launch_bounds__(64,3) -> ~3 waves/SIMD resident.
// q-stripe 64 per wave; b = id&3 XCD-pinned (1.5MB L2-resident set).
// Per 64-l chunk: PV(it-1) 32 MFMA ; S(it) 32 MFMA -> exp2 -> LDS.
// Ynum stored in bf16 fragment order (halves write+read traffic).
// ---------------------------------------------------------------------------
__global__ __launch_bounds__(64, 3) void attn_kernel(
    const u16* __restrict__ fkF, const u16* __restrict__ hkF,
    const u16* __restrict__ fvF, u16* __restrict__ Ynum,
    float* __restrict__ den) {
  constexpr int LL = 4096, CH = 64, NITER = (LL / NSPLIT) / CH;  // 4
  const int lane = threadIdx.x;
  const int q15 = lane & 15;
  const int quad = lane >> 4;
  const int id = blockIdx.x;
  const int b = id & 3;
  const int qblk = (id >> 2) & 63;      // 64 q each
  const int split = id >> 8;            // 0..15
  const int l0base = split * (LL / NSPLIT);

  __shared__ __align__(16) char sP[8192];  // P[l64][q64] in read-order

  // hk B-frags, persistent; contiguous 1KB loads from hkF
  bf16x8 hkf[4][2];
#pragma unroll
  for (int j = 0; j < 4; ++j)
#pragma unroll
    for (int ks = 0; ks < 2; ++ks)
      hkf[j][ks] = *reinterpret_cast<const bf16x8*>(
          hkF + ((size_t)((b * 256 + qblk * 4 + j) * 2 + ks)) * 512 + lane * 8);

  f32x4 Yacc[4][4];
#pragma unroll
  for (int mm = 0; mm < 4; ++mm)
#pragma unroll
    for (int nn = 0; nn < 4; ++nn) Yacc[mm][nn] = (f32x4){0.f, 0.f, 0.f, 0.f};
  float dsum[4] = {0.f, 0.f, 0.f, 0.f};

  const int wbase = (quad >> 1) * 256 + q15 * 16 + (quad & 1) * 8;
  const int rbase = lane * 16;

  bf16x8 fkf[4][2];  // A-frags of fk for current chunk (strip s = 16 l)
  bf16x8 af[4][2];   // A-frags of fv for chunk it-1 at PV time

  auto loadFK = [&](int l0) {
    const int t0 = l0 >> 4;
#pragma unroll
    for (int s = 0; s < 4; ++s)
#pragma unroll
      for (int ks = 0; ks < 2; ++ks)
        fkf[s][ks] = *reinterpret_cast<const bf16x8*>(
            fkF + ((size_t)((b * 256 + t0 + s) * 2 + ks)) * 512 + lane * 8);
  };
  auto loadAF = [&](int l0) {
    const int cl = l0 >> 6;
#pragma unroll
    for (int mm = 0; mm < 4; ++mm)
#pragma unroll
      for (int ks = 0; ks < 2; ++ks)
        af[mm][ks] = *reinterpret_cast<const bf16x8*>(
            fvF + ((size_t)(((b * 4 + mm) * 64 + cl) * 2 + ks)) * 512 + lane * 8);
  };
  auto Sphase = [&]() {
#pragma unroll
    for (int s = 0; s < 4; ++s) {
      f32x4 accS[4];
#pragma unroll
      for (int jj = 0; jj < 4; ++jj) accS[jj] = (f32x4){0.f, 0.f, 0.f, 0.f};
#pragma unroll
      for (int ks = 0; ks < 2; ++ks)
#pragma unroll
        for (int jj = 0; jj < 4; ++jj)
          accS[jj] = MFMA16(fkf[s][ks], hkf[jj][ks], accS[jj]);
      char* wp = sP + (s >> 1) * 4096 + (s & 1) * 512 + wbase;
#pragma unroll
      for (int jj = 0; jj < 4; ++jj) {
        bf16x4 pk;
        float ds = 0.f;
#pragma unroll
        for (int r = 0; r < 4; ++r) {
          float e = __builtin_amdgcn_exp2f(accS[jj][r]);
          pk[r] = (__bf16)e;
          ds += e;
        }
        dsum[jj] += ds;
        *reinterpret_cast<uint32x2*>(wp + jj * 1024) =
            __builtin_bit_cast(uint32x2, pk);
      }
    }
  };
  auto PVphase = [&]() {
#pragma unroll
    for (int ks = 0; ks < 2; ++ks) {
      bf16x8 bfr[4];
#pragma unroll
      for (int nn = 0; nn < 4; ++nn)
        bfr[nn] = *reinterpret_cast<const bf16x8*>(
            sP + ks * 4096 + nn * 1024 + rbase);
#pragma unroll
      for (int mm = 0; mm < 4; ++mm)
#pragma unroll
        for (int nn = 0; nn < 4; ++nn)
          Yacc[mm][nn] = MFMA16(af[mm][ks], bfr[nn], Yacc[mm][nn]);
    }
  };

  // --- prologue: S(0) into sP ---
  loadFK(l0base);
  loadAF(l0base);
  Sphase();
  loadFK(l0base + CH);

  // --- steady: PV(it-1) reads sP, then S(it) overwrites it (wave-ordered) ---
#pragma unroll
  for (int it = 1; it < NITER; ++it) {
    PVphase();                                    // consumes P(it-1), af(it-1)
    Sphase();                                     // uses fkf(it), writes sP
    loadAF(l0base + it * CH);                     // af for next PV
    if (it + 1 < NITER) loadFK(l0base + (it + 1) * CH);
  }
  PVphase();  // last chunk

  // --- epilogue: denom quad-reduction + bf16 fragment-order Ynum ---
  const size_t slot = ((size_t)split * 4 + b) * 64 + qblk;
#pragma unroll
  for (int jj = 0; jj < 4; ++jj) {
    float d = dsum[jj];
    d += __shfl_xor(d, 16, 64);
    d += __shfl_xor(d, 32, 64);
    if (quad == 0) den[slot * 64 + jj * 16 + q15] = d;
  }
  u16* Yo = Ynum + slot * 4096;
#pragma unroll
  for (int mm = 0; mm < 4; ++mm)
#pragma unroll
    for (int nn = 0; nn < 4; ++nn) {
      bf16x4 o;
#pragma unroll
      for (int r = 0; r < 4; ++r) o[r] = (__bf16)Yacc[mm][nn][r];
      *reinterpret_cast<uint32x2*>(Yo + (mm * 4 + nn) * 256 + lane * 4) =
          __builtin_bit_cast(uint32x2, o);
    }
}

// ---------------------------------------------------------------------------
// Combine the NSPLIT l-splits and normalize. out[b][v][q], 1M elements.
// Ynum bf16 fragment order: [slot][mm4][nn4][lane64][r4].
// ---------------------------------------------------------------------------
__global__ __launch_bounds__(256) void combine_kernel(
    const u16* __restrict__ Yn, const float* __restrict__ dn,
    float* __restrict__ out) {
  const int idx = blockIdx.x * 256 + threadIdx.x;
  const int q = idx & 4095;
  const int v = (idx >> 12) & 63;
  const int b = idx >> 18;
  const int qb = q >> 6;
  const int mm = v >> 4, md = (v >> 2) & 3, r = v & 3;
  const int nn = (q >> 4) & 3, lane = md * 16 + (q & 15);
  const int off = (mm * 4 + nn) * 256 + lane * 4 + r;
  float num = 0.f, d = 1e-16f;
#pragma unroll
  for (int s = 0; s < NSPLIT; ++s) {
    const size_t slot = ((size_t)s * 4 + b) * 64 + qb;
    num += (float)__builtin_bit_cast(__bf16, Yn[slot * 4096 + off]);
    d += dn[slot * 64 + (q & 63)];
  }
  out[idx] = num / d;
}

extern "C" void kernel_launch(void* const* d_in, const int* in_sizes, int n_in,
                              void* d_out, int out_size, void* d_ws,
                              size_t ws_size, hipStream_t stream) {
  const float* field = (const float*)d_in[0];
  const float* query = (const float*)d_in[1];
  const float* Wfk = (const float*)d_in[2];
  const float* bfk = (const float*)d_in[3];
  const float* Wfv = (const float*)d_in[4];
  const float* bfv = (const float*)d_in[5];
  const float* Wqk = (const float*)d_in[6];
  const float* bqk = (const float*)d_in[7];
  float* out = (float*)d_out;

  char* ws = (char*)d_ws;
  u16* fkF = (u16*)(ws);                       // 2 MB  A-frag order, scaled
  u16* hkF = (u16*)(ws + (2ull << 20));        // 2 MB  B-frag order
  u16* fvF = (u16*)(ws + (4ull << 20));        // 2 MB  A-frag order
  u16* Ynum = (u16*)(ws + (6ull << 20));       // 32 MB bf16 [4096 slots][4096]
  float* den = (float*)(ws + (38ull << 20));   // 1 MB  [4096 slots][64]

  proj_kernel<<<dim3(768), 64, 0, stream>>>(field, query, Wfk, bfk, Wfv, bfv,
                                            Wqk, bqk, fkF, fvF, hkF);
  attn_kernel<<<dim3(4096), 64, 0, stream>>>(fkF, hkF, fvF, Ynum, den);
  combine_kernel<<<dim3(4096), 256, 0, stream>>>(Ynum, den, out);
}

// Round 11
// 113.634 us; speedup vs baseline: 2.5384x; 2.5384x over previous
//
#include <hip/hip_runtime.h>
#include <hip/hip_bf16.h>

typedef unsigned short u16;
typedef __bf16 bf16x8 __attribute__((ext_vector_type(8)));
typedef __bf16 bf16x4 __attribute__((ext_vector_type(4)));
typedef float f32x4 __attribute__((ext_vector_type(4)));
typedef unsigned int uint32x2 __attribute__((ext_vector_type(2)));

#define MFMA16(a, b, c) __builtin_amdgcn_mfma_f32_16x16x32_bf16(a, b, c, 0, 0, 0)

// exp(z/8) = exp2(z * log2(e)/8); folded into fkF at projection time.
#define FK_SCALE 0.1803368801111204f  // 0.125 * log2(e)

#define NSPLIT 8

// ---------------------------------------------------------------------------
// MFMA projections (bf16 in / fp32 acc). One wave per (proj, b, 64-l chunk):
// grid 768 x 64thr, bx = p*256 + b*64 + chunk.
//  p=0 fk: C[kout][l] = Wfk(A) . field(B), scaled, +bias -> fkF (A-frag order)
//  p=1 fv: C[l][v]    = field(A) . Wfv(B), +bias         -> fvF (A-frag order)
//  p=2 hk: C[kout][q] = Wqk(A) . query(B), +bias         -> hkF (B-frag order)
// ---------------------------------------------------------------------------
__global__ __launch_bounds__(64, 2) void proj_kernel(
    const float* __restrict__ field, const float* __restrict__ query,
    const float* __restrict__ Wfk, const float* __restrict__ bfk,
    const float* __restrict__ Wfv, const float* __restrict__ bfv,
    const float* __restrict__ Wqk, const float* __restrict__ bqk,
    u16* __restrict__ fkF, u16* __restrict__ fvF, u16* __restrict__ hkF) {
  const int lane = threadIdx.x;
  const int q15 = lane & 15, quad = lane >> 4;
  const int bx = blockIdx.x;
  const int p = bx >> 8;          // 0=fk, 1=fv, 2=hk
  const int b = (bx >> 6) & 3;
  const int l0 = (bx & 63) * 64;

  const float* src  = (p == 2) ? query : field;
  const float* W    = (p == 0) ? Wfk : (p == 1) ? Wfv : Wqk;
  const float* bias = (p == 0) ? bfk : (p == 1) ? bfv : bqk;
  const float* sp = src + (size_t)b * (128 * 4096);

  // src frags: p!=1: B[k=f][n=l]; p==1: A[m=l][k=f] (same lane mapping).
  bf16x8 fr1[4][4];
#pragma unroll
  for (int t = 0; t < 4; ++t)
#pragma unroll
    for (int ks = 0; ks < 4; ++ks) {
      const float* pp = sp + (size_t)(ks * 32 + quad * 8) * 4096 + l0 + t * 16 + q15;
      bf16x8 v;
#pragma unroll
      for (int j = 0; j < 8; ++j) v[j] = (__bf16)pp[(size_t)j * 4096];
      fr1[t][ks] = v;
    }

  // W frags: p!=1: A[m=kout][k=f]; p==1: B[k=f][n=v].
  bf16x8 fr2[4][4];
#pragma unroll
  for (int t = 0; t < 4; ++t)
#pragma unroll
    for (int ks = 0; ks < 4; ++ks) {
      const float* pp = W + (size_t)(t * 16 + q15) * 128 + ks * 32 + quad * 8;
      f32x4 w0 = *reinterpret_cast<const f32x4*>(pp);
      f32x4 w1 = *reinterpret_cast<const f32x4*>(pp + 4);
      bf16x8 v;
#pragma unroll
      for (int j = 0; j < 4; ++j) { v[j] = (__bf16)w0[j]; v[4 + j] = (__bf16)w1[j]; }
      fr2[t][ks] = v;
    }

#pragma unroll
  for (int nn = 0; nn < 4; ++nn) {
    f32x4 Cn[4];
#pragma unroll
    for (int mm = 0; mm < 4; ++mm) Cn[mm] = (f32x4){0.f, 0.f, 0.f, 0.f};
#pragma unroll
    for (int ks = 0; ks < 4; ++ks)
#pragma unroll
      for (int mm = 0; mm < 4; ++mm)
        Cn[mm] = (p == 1) ? MFMA16(fr1[mm][ks], fr2[nn][ks], Cn[mm])
                          : MFMA16(fr2[mm][ks], fr1[nn][ks], Cn[mm]);

    if (p == 1) {
      // C rows = l = l0+mm*16+quad*4+r, cols = v = nn*16+q15
      const float bv = bias[nn * 16 + q15];
#pragma unroll
      for (int mm = 0; mm < 4; ++mm) {
        bf16x4 o;
#pragma unroll
        for (int r = 0; r < 4; ++r) o[r] = (__bf16)(Cn[mm][r] + bv);
        u16* dst = fvF +
            ((size_t)((b * 4 + nn) * 64 + (l0 >> 6)) * 2 + (mm >> 1)) * 512 +
            (((2 * mm + (quad >> 1)) & 3) * 16 + q15) * 8 + (quad & 1) * 4;
        *reinterpret_cast<uint32x2*>(dst) = __builtin_bit_cast(uint32x2, o);
      }
    } else {
      // C rows = kout = mm*16+quad*4+r, cols = (l or q) = l0+nn*16+q15.
      const float cs = (p == 0) ? FK_SCALE : 1.0f;
      u16* outF = (p == 0) ? fkF : hkF;
#pragma unroll
      for (int mm = 0; mm < 4; ++mm) {
        f32x4 bz = *reinterpret_cast<const f32x4*>(bias + mm * 16 + quad * 4);
        bf16x4 o;
#pragma unroll
        for (int r = 0; r < 4; ++r) o[r] = (__bf16)((Cn[mm][r] + bz[r]) * cs);
        u16* dst = outF +
            ((size_t)((b * 256 + (l0 >> 4) + nn) * 2) + (mm >> 1)) * 512 +
            (((2 * mm + (quad >> 1)) & 3) * 16 + q15) * 8 + (quad & 1) * 4;
        *reinterpret_cast<uint32x2*>(dst) = __builtin_bit_cast(uint32x2, o);
      }
    }
  }
}

// ---------------------------------------------------------------------------
// Attention: barrier-free, cross-chunk pipelined, q-stripe 64 per wave.
// EXACT R9 structure (117.9us best): NSPLIT=8, grid 2048, (64,2) -- the
// accumulator set (~180 live regs) fits 2 waves/SIMD; (64,3) provably
// spills to scratch (R10: 481MB of HBM spill traffic, 2x slowdown).
// Double-buffered 8KB LDS; PV(it-1) overlaps S(it); 1KB contiguous
// fragment loads; XCD-pinned b. Only delta vs R9: Ynum stored bf16.
// ---------------------------------------------------------------------------
__global__ __launch_bounds__(64, 2) void attn_kernel(
    const u16* __restrict__ fkF, const u16* __restrict__ hkF,
    const u16* __restrict__ fvF, u16* __restrict__ Ynum,
    float* __restrict__ den) {
  constexpr int LL = 4096, CH = 64, NITER = (LL / NSPLIT) / CH;  // 8
  const int lane = threadIdx.x;
  const int q15 = lane & 15;
  const int quad = lane >> 4;
  const int id = blockIdx.x;
  const int b = id & 3;
  const int qblk = (id >> 2) & 63;      // 64 q each
  const int split = id >> 8;
  const int l0base = split * (LL / NSPLIT);

  __shared__ __align__(16) char sP[2][8192];  // P[l64][q64] in read-order

  // hk B-frags, persistent; contiguous 1KB loads from hkF
  bf16x8 hkf[4][2];
#pragma unroll
  for (int j = 0; j < 4; ++j)
#pragma unroll
    for (int ks = 0; ks < 2; ++ks)
      hkf[j][ks] = *reinterpret_cast<const bf16x8*>(
          hkF + ((size_t)((b * 256 + qblk * 4 + j) * 2 + ks)) * 512 + lane * 8);

  bf16x8 ones;
#pragma unroll
  for (int j = 0; j < 8; ++j) ones[j] = (__bf16)1.0f;

  f32x4 Yacc[4][4];
#pragma unroll
  for (int mm = 0; mm < 4; ++mm)
#pragma unroll
    for (int nn = 0; nn < 4; ++nn) Yacc[mm][nn] = (f32x4){0.f, 0.f, 0.f, 0.f};
  f32x4 denAcc[4];
#pragma unroll
  for (int nn = 0; nn < 4; ++nn) denAcc[nn] = (f32x4){0.f, 0.f, 0.f, 0.f};

  const int wbase = (quad >> 1) * 256 + q15 * 16 + (quad & 1) * 8;
  const int rbase = lane * 16;

  bf16x8 fkf[4][2];  // A-frags of fk for current chunk (strip s = 16 l)
  bf16x8 af[4][2];   // A-frags of fv for chunk it-1 at PV time

  auto loadFK = [&](int l0) {
    const int t0 = l0 >> 4;
#pragma unroll
    for (int s = 0; s < 4; ++s)
#pragma unroll
      for (int ks = 0; ks < 2; ++ks)
        fkf[s][ks] = *reinterpret_cast<const bf16x8*>(
            fkF + ((size_t)((b * 256 + t0 + s) * 2 + ks)) * 512 + lane * 8);
  };
  auto loadAF = [&](int l0) {
    const int cl = l0 >> 6;
#pragma unroll
    for (int mm = 0; mm < 4; ++mm)
#pragma unroll
      for (int ks = 0; ks < 2; ++ks)
        af[mm][ks] = *reinterpret_cast<const bf16x8*>(
            fvF + ((size_t)(((b * 4 + mm) * 64 + cl) * 2 + ks)) * 512 + lane * 8);
  };
  auto Sphase = [&](char* sPb) {
#pragma unroll
    for (int s = 0; s < 4; ++s) {
      f32x4 accS[4];
#pragma unroll
      for (int jj = 0; jj < 4; ++jj) accS[jj] = (f32x4){0.f, 0.f, 0.f, 0.f};
#pragma unroll
      for (int ks = 0; ks < 2; ++ks)
#pragma unroll
        for (int jj = 0; jj < 4; ++jj)
          accS[jj] = MFMA16(fkf[s][ks], hkf[jj][ks], accS[jj]);
      char* wp = sPb + (s >> 1) * 4096 + (s & 1) * 512 + wbase;
#pragma unroll
      for (int jj = 0; jj < 4; ++jj) {
        bf16x4 pk;
#pragma unroll
        for (int r = 0; r < 4; ++r)
          pk[r] = (__bf16)__builtin_amdgcn_exp2f(accS[jj][r]);
        *reinterpret_cast<uint32x2*>(wp + jj * 1024) =
            __builtin_bit_cast(uint32x2, pk);
      }
    }
  };
  auto PVphase = [&](const char* sPr) {
#pragma unroll
    for (int ks = 0; ks < 2; ++ks) {
      bf16x8 bfr[4];
#pragma unroll
      for (int nn = 0; nn < 4; ++nn)
        bfr[nn] = *reinterpret_cast<const bf16x8*>(
            sPr + ks * 4096 + nn * 1024 + rbase);
#pragma unroll
      for (int nn = 0; nn < 4; ++nn)
        denAcc[nn] = MFMA16(ones, bfr[nn], denAcc[nn]);
#pragma unroll
      for (int mm = 0; mm < 4; ++mm)
#pragma unroll
        for (int nn = 0; nn < 4; ++nn)
          Yacc[mm][nn] = MFMA16(af[mm][ks], bfr[nn], Yacc[mm][nn]);
    }
  };

  // --- prologue ---
  loadFK(l0base);
  loadAF(l0base);
  Sphase(sP[0]);
  loadFK(l0base + CH);

  // --- steady state: PV(it-1) overlaps S(it); loads one chunk ahead ---
#pragma unroll 2
  for (int it = 1; it < NITER; ++it) {
    const int l0 = l0base + it * CH;
    Sphase(sP[it & 1]);
    if (it + 1 < NITER) loadFK(l0 + CH);
    PVphase(sP[(it - 1) & 1]);
    loadAF(l0);
  }
  PVphase(sP[(NITER - 1) & 1]);

  // --- epilogue: bf16 fragment-order Ynum (coalesced 8B) + denom ---
  const size_t slot = ((size_t)split * 4 + b) * 64 + qblk;
  if (quad == 0) {
#pragma unroll
    for (int nn = 0; nn < 4; ++nn)
      den[slot * 64 + nn * 16 + q15] = denAcc[nn][0];  // all C rows equal
  }
  u16* Yo = Ynum + slot * 4096;
#pragma unroll
  for (int mm = 0; mm < 4; ++mm)
#pragma unroll
    for (int nn = 0; nn < 4; ++nn) {
      bf16x4 o;
#pragma unroll
      for (int r = 0; r < 4; ++r) o[r] = (__bf16)Yacc[mm][nn][r];
      *reinterpret_cast<uint32x2*>(Yo + (mm * 4 + nn) * 256 + lane * 4) =
          __builtin_bit_cast(uint32x2, o);
    }
}

// ---------------------------------------------------------------------------
// Combine the NSPLIT l-splits and normalize. out[b][v][q], 1M elements.
// Ynum bf16 fragment order: [slot][mm4][nn4][lane64][r4].
// ---------------------------------------------------------------------------
__global__ __launch_bounds__(256) void combine_kernel(
    const u16* __restrict__ Yn, const float* __restrict__ dn,
    float* __restrict__ out) {
  const int idx = blockIdx.x * 256 + threadIdx.x;
  const int q = idx & 4095;
  const int v = (idx >> 12) & 63;
  const int b = idx >> 18;
  const int qb = q >> 6;
  const int mm = v >> 4, md = (v >> 2) & 3, r = v & 3;
  const int nn = (q >> 4) & 3, lane = md * 16 + (q & 15);
  const int off = (mm * 4 + nn) * 256 + lane * 4 + r;
  float num = 0.f, d = 1e-16f;
#pragma unroll
  for (int s = 0; s < NSPLIT; ++s) {
    const size_t slot = ((size_t)s * 4 + b) * 64 + qb;
    num += (float)__builtin_bit_cast(__bf16, Yn[slot * 4096 + off]);
    d += dn[slot * 64 + (q & 63)];
  }
  out[idx] = num / d;
}

extern "C" void kernel_launch(void* const* d_in, const int* in_sizes, int n_in,
                              void* d_out, int out_size, void* d_ws,
                              size_t ws_size, hipStream_t stream) {
  const float* field = (const float*)d_in[0];
  const float* query = (const float*)d_in[1];
  const float* Wfk = (const float*)d_in[2];
  const float* bfk = (const float*)d_in[3];
  const float* Wfv = (const float*)d_in[4];
  const float* bfv = (const float*)d_in[5];
  const float* Wqk = (const float*)d_in[6];
  const float* bqk = (const float*)d_in[7];
  float* out = (float*)d_out;

  char* ws = (char*)d_ws;
  u16* fkF = (u16*)(ws);                       // 2 MB  A-frag order, scaled
  u16* hkF = (u16*)(ws + (2ull << 20));        // 2 MB  B-frag order
  u16* fvF = (u16*)(ws + (4ull << 20));        // 2 MB  A-frag order
  u16* Ynum = (u16*)(ws + (6ull << 20));       // 16 MB bf16 [2048 slots][4096]
  float* den = (float*)(ws + (22ull << 20));   // 512 KB [2048 slots][64]

  proj_kernel<<<dim3(768), 64, 0, stream>>>(field, query, Wfk, bfk, Wfv, bfv,
                                            Wqk, bqk, fkF, fvF, hkF);
  attn_kernel<<<dim3(2048), 64, 0, stream>>>(fkF, hkF, fvF, Ynum, den);
  combine_kernel<<<dim3(4096), 256, 0, stream>>>(Ynum, den, out);
}